// Round 8
// baseline (497.160 us; speedup 1.0000x reference)
//
#include <hip/hip_runtime.h>
#include <hip/hip_fp16.h>
#include <cmath>

#define NN 20000
#define FF 128
#define EE 32768
#define RR 8

#define OUT_X (NN*FF)            // 2,560,000
#define OUT_M (NN*FF + NN*12)    // 2,800,000

typedef _Float16 half8 __attribute__((ext_vector_type(8)));
typedef float f32x4 __attribute__((ext_vector_type(4)));

#define MFMA16(a,b,c) __builtin_amdgcn_mfma_f32_16x16x32_f16(a, b, c, 0, 0, 0)

__device__ __forceinline__ float silu_f(float x) {
    return x / (1.0f + __expf(-x));
}
__device__ __forceinline__ unsigned short f2h(float x) {
    _Float16 h = (_Float16)x;
    return __builtin_bit_cast(unsigned short, h);
}
__device__ __forceinline__ float h2f(unsigned short u) {
    return (float)__builtin_bit_cast(_Float16, u);
}

__device__ __forceinline__ void seg_atomic(unsigned short* p, unsigned bits) {
#if __has_builtin(__builtin_amdgcn_flat_atomic_fadd_v2f16)
    typedef _Float16 v2h __attribute__((ext_vector_type(2)));
    v2h v = __builtin_bit_cast(v2h, bits);
    __builtin_amdgcn_flat_atomic_fadd_v2f16((v2h*)p, v);
#else
    __half2 v = __builtin_bit_cast(__half2, bits);
    unsafeAtomicAdd((__half2*)p, v);
#endif
}

// ---- column-split helpers: wave w covers 4 m-tiles x n-tiles {2w,2w+1} ----
__device__ __forceinline__ void zero42(f32x4 acc[4][2]) {
#pragma unroll
    for (int m = 0; m < 4; m++) { acc[m][0] = (f32x4)0.f; acc[m][1] = (f32x4)0.f; }
}

__device__ __forceinline__ void mfma_chunk4(const unsigned short* __restrict__ Bp, int c,
                                            int wid, int q, int n16,
                                            const half8 a[4], f32x4 acc[4][2])
{
    const unsigned short* bb = Bp + (size_t)(((c * 8 + 2 * wid) * 4) + q) * 128 + n16 * 8;
    half8 b0 = *(const half8*)bb;
    half8 b1 = *(const half8*)(bb + 512);
#pragma unroll
    for (int m = 0; m < 4; m++) {
        acc[m][0] = MFMA16(a[m], b0, acc[m][0]);
        acc[m][1] = MFMA16(a[m], b1, acc[m][1]);
    }
}

// A from LDS tile (64 x NCH*32, stride 136)
template<int NCH>
__device__ __forceinline__ void gemm_lds4(const unsigned short* __restrict__ Bp,
                                          const unsigned short* sA,
                                          int wid, int q, int n16, f32x4 acc[4][2])
{
#pragma unroll
    for (int c = 0; c < NCH; c++) {
        half8 a[4];
#pragma unroll
        for (int m = 0; m < 4; m++)
            a[m] = *(const half8*)(sA + (m * 16 + n16) * 136 + c * 32 + q * 8);
        mfma_chunk4(Bp, c, wid, q, n16, a, acc);
    }
}

// C/D layout: col = lane&15, row = (lane>>4)*4 + reg
__device__ __forceinline__ void store_act4(f32x4 acc[4][2], const float* __restrict__ bias,
                                           unsigned short* sOut, int n16, int q, int wid,
                                           bool dosilu)
{
#pragma unroll
    for (int i = 0; i < 2; i++) {
        const int n = (2 * wid + i) * 16 + n16;
        const float bb = bias[n];
#pragma unroll
        for (int m = 0; m < 4; m++)
#pragma unroll
            for (int rr = 0; rr < 4; rr++) {
                float v = acc[m][i][rr] + bb;
                if (dosilu) v = silu_f(v);
                sOut[(m * 16 + q * 4 + rr) * 136 + n] = f2h(v);
            }
    }
}

// ============ prep: h -> f16 ============
__global__ __launch_bounds__(256) void k_cvt_h(const float* __restrict__ h,
                                               unsigned short* __restrict__ h_bf)
{
    const int i = (blockIdx.x * 256 + threadIdx.x) * 4;
    float4 v = *(const float4*)(h + i);
    unsigned short u[4] = { f2h(v.x), f2h(v.y), f2h(v.z), f2h(v.w) };
    *(uint2*)(h_bf + i) = *(const uint2*)u;
}

// ============ fused weight pack ============
__device__ __forceinline__ void pack_block(const float* __restrict__ Wb,
                                           unsigned short* __restrict__ db,
                                           int K, int remap, int blk)
{
    const int p = blk * 256 + threadIdx.x;
    const int j = p & 7, n16 = (p >> 3) & 15, q = (p >> 7) & 3, t = (p >> 9) & 7, c = p >> 12;
    int k = c * 32 + q * 8 + j;
    if (remap) k = (k < 128) ? k : (k < 256) ? (k + 1) : (k == 256 ? 128 : K);
    const int n = t * 16 + n16;
    db[p] = f2h((k < K) ? Wb[(size_t)k * 128 + n] : 0.f);
}

__global__ __launch_bounds__(256) void k_pack_all(
    const float* __restrict__ Wm1, const float* __restrict__ Wm2,
    const float* __restrict__ Wn1, const float* __restrict__ Wn2,
    const float* __restrict__ We1, const float* __restrict__ Wc1,
    const float* __restrict__ Wrel, const float* __restrict__ Wc2,
    unsigned short* __restrict__ Wm1p, unsigned short* __restrict__ Wm2p,
    unsigned short* __restrict__ Wn1p, unsigned short* __restrict__ Wn2p,
    unsigned short* __restrict__ We1p, unsigned short* __restrict__ Wc1p,
    unsigned short* __restrict__ Wrelp, unsigned short* __restrict__ Wc2p)
{
    const int b = blockIdx.x;
    if (b < 144)        pack_block(Wm1, Wm1p, 273, 0, b);
    else if (b < 208)   pack_block(Wm2, Wm2p, 128, 0, b - 144);
    else if (b < 336)   pack_block(Wn1, Wn1p, 256, 0, b - 208);
    else if (b < 400)   pack_block(Wn2, Wn2p, 128, 0, b - 336);
    else if (b < 544)   pack_block(We1, We1p, 257, 1, b - 400);
    else if (b < 1056) {
        const int bb = b - 544, batch = bb >> 6;
        pack_block(Wc1 + (size_t)batch * 16384, Wc1p + (size_t)batch * 16384, 128, 0, bb & 63);
    } else if (b < 1568) {
        const int bb = b - 1056, batch = bb >> 6;
        pack_block(Wrel + (size_t)batch * 16384, Wrelp + (size_t)batch * 16384, 128, 0, bb & 63);
    } else {
        const int bb = b - 1568, r = bb >> 3;
        const int p = (bb & 7) * 256 + threadIdx.x;
        const int j = p & 7, n16 = (p >> 3) & 15, q = (p >> 7) & 3, c = (p >> 9) & 3;
        const int k = c * 32 + q * 8 + j;
        float v = (n16 < 4) ? Wc2[(size_t)r * 512 + k * 4 + n16] * 256.0f : 0.f;
        Wc2p[(size_t)r * 2048 + p] = f2h(v);
    }
}

// ============ radial norm-squared accumulation ============
__global__ __launch_bounds__(256) void k_norm(const float* __restrict__ coord,
                                              const int* __restrict__ edges,
                                              float* __restrict__ nsq)
{
    const int r = blockIdx.x;
    const int tid = threadIdx.x;
    const int* rows = edges + r * 2 * EE;
    const int* cols = rows + EE;
    float acc[16];
#pragma unroll
    for (int i = 0; i < 16; i++) acc[i] = 0.f;
    const int e0 = blockIdx.y * 1024;
    for (int e = e0 + tid; e < e0 + 1024; e += 256) {
        const float4* cr = (const float4*)(coord + (size_t)rows[e] * 12);
        const float4* cc = (const float4*)(coord + (size_t)cols[e] * 12);
        float4 a0 = cr[0], a1 = cr[1], a2 = cr[2];
        float4 b0 = cc[0], b1 = cc[1], b2 = cc[2];
        float cd[12] = { a0.x-b0.x, a0.y-b0.y, a0.z-b0.z, a0.w-b0.w,
                         a1.x-b1.x, a1.y-b1.y, a1.z-b1.z, a1.w-b1.w,
                         a2.x-b2.x, a2.y-b2.y, a2.z-b2.z, a2.w-b2.w };
#pragma unroll
        for (int c = 0; c < 4; c++)
#pragma unroll
            for (int d = 0; d < 4; d++) {
                float v = cd[c*3]*cd[d*3] + cd[c*3+1]*cd[d*3+1] + cd[c*3+2]*cd[d*3+2];
                acc[c*4+d] += v * v;
            }
    }
#pragma unroll
    for (int i = 0; i < 16; i++) {
        float v = acc[i];
        for (int off = 32; off; off >>= 1) v += __shfl_down(v, off, 64);
        if ((tid & 63) == 0) atomicAdd(&nsq[r * 16 + i], v);
    }
}

__global__ void k_invnorm(const float* __restrict__ nsq, float* __restrict__ inv_norm)
{
    int i = threadIdx.x;
    if (i < RR * 16) {
        float n = sqrtf(nsq[i]);
        inv_norm[i] = 1.0f / fmaxf(n, 1e-12f);
    }
}

// ============ message MLP + phi + scatters (64 edges, 256 threads) ============
// Single activation buffer shT (t1 -> ef -> hid), full barriers between phases.
// Everything else identical to R7 (dim3 grid, natural register allocation).
__global__ __launch_bounds__(256, 2) void k_msg(
    const unsigned short* __restrict__ h_bf, const float* __restrict__ coord,
    const float* __restrict__ eattr, const int* __restrict__ edges,
    const float* __restrict__ inv_norm,
    const unsigned short* __restrict__ Wm1p, const float* __restrict__ bm1,
    const unsigned short* __restrict__ Wm2p, const float* __restrict__ bm2,
    const unsigned short* __restrict__ Wc1p, const float* __restrict__ bc1,
    const unsigned short* __restrict__ Wc2p,
    float* __restrict__ sAccum, float* __restrict__ cnt,
    unsigned short* __restrict__ seg)
{
    __shared__ __align__(16) unsigned short shT[64 * 136];  // t1 -> ef -> hid
    __shared__ float shCd[64 * 12];
    __shared__ float shPhi[64 * 4];
    __shared__ int shRow[64], shCol[64];
    __shared__ float shInv[16];

    const int tid = threadIdx.x;
    const int lane = tid & 63, wid = tid >> 6;
    const int n16 = lane & 15, q = lane >> 4;
    const int ko = q * 8;
    const int r = blockIdx.y;
    const int e0 = blockIdx.x * 64;

    if (tid < 64) shRow[tid] = edges[r * 2 * EE + e0 + tid];
    else if (tid < 128) shCol[tid - 64] = edges[r * 2 * EE + EE + e0 + (tid - 64)];
    else if (tid < 144) shInv[tid - 128] = inv_norm[r * 16 + (tid - 128)];
    __syncthreads();                                       // B1

    int rowN[4], colN[4];
#pragma unroll
    for (int m = 0; m < 4; m++) {
        rowN[m] = shRow[m * 16 + n16];
        colN[m] = shCol[m * 16 + n16];
    }

    // chunk-8 A fragments (radial|eattr|pad) in registers; q==0 lanes park cd in shCd
    half8 aX[4];
#pragma unroll
    for (int m = 0; m < 4; m++) aX[m] = (half8)(_Float16)0.0f;
    if (q < 2) {
        float inv[8];
#pragma unroll
        for (int j = 0; j < 8; j++) inv[j] = shInv[q * 8 + j];
#pragma unroll
        for (int m = 0; m < 4; m++) {
            const float* cr = coord + (size_t)rowN[m] * 12;
            const float* cc = coord + (size_t)colN[m] * 12;
            float cd[12];
#pragma unroll
            for (int i2 = 0; i2 < 12; i2++) cd[i2] = cr[i2] - cc[i2];
            if (q == 0) {
#pragma unroll
                for (int i2 = 0; i2 < 12; i2++) shCd[(m * 16 + n16) * 12 + i2] = cd[i2];
            }
#pragma unroll
            for (int j = 0; j < 8; j++) {
                const int kk = q * 8 + j, c = kk >> 2, d = kk & 3;
                float v = cd[c*3]*cd[d*3] + cd[c*3+1]*cd[d*3+1] + cd[c*3+2]*cd[d*3+2];
                aX[m][j] = (_Float16)(v * inv[j]);
            }
        }
    } else if (q == 2) {
#pragma unroll
        for (int m = 0; m < 4; m++)
            aX[m][0] = (_Float16)eattr[(size_t)r * EE + e0 + m * 16 + n16];
    }

    // ---- layer 1: msg @ Wm1 -> t1 ----
    f32x4 acc[4][2];
    zero42(acc);
#pragma unroll
    for (int c = 0; c < 4; c++) {
        half8 a[4];
#pragma unroll
        for (int m = 0; m < 4; m++)
            a[m] = *(const half8*)(h_bf + (size_t)rowN[m] * 128 + c * 32 + ko);
        mfma_chunk4(Wm1p, c, wid, q, n16, a, acc);
    }
#pragma unroll
    for (int c = 0; c < 4; c++) {
        half8 a[4];
#pragma unroll
        for (int m = 0; m < 4; m++)
            a[m] = *(const half8*)(h_bf + (size_t)colN[m] * 128 + c * 32 + ko);
        mfma_chunk4(Wm1p, c + 4, wid, q, n16, a, acc);
    }
    mfma_chunk4(Wm1p, 8, wid, q, n16, aX, acc);
    store_act4(acc, bm1, shT, n16, q, wid, true);          // t1 -> shT
    __syncthreads();                                       // B2: t1 ready

    // ---- layer 2: t1 @ Wm2 -> ef ----
    zero42(acc);
    gemm_lds4<4>(Wm2p, shT, wid, q, n16, acc);
    __syncthreads();                                       // B3: t1 fully consumed
    store_act4(acc, bm2, shT, n16, q, wid, true);          // ef -> shT
    __syncthreads();                                       // B4: ef ready

    // ---- layer 3: ef @ Wc1[r] -> hid ; seg += ef ----
    zero42(acc);
    gemm_lds4<4>(Wc1p + (size_t)r * 16384, shT, wid, q, n16, acc);
    {
        unsigned short* segr = seg + (size_t)r * NN * 128;
        for (int it = tid; it < 64 * 64; it += 256) {
            const int e = it >> 6, jj = it & 63;
            const unsigned bits = *(const unsigned*)(shT + e * 136 + jj * 2);
            seg_atomic(segr + (size_t)shRow[e] * 128 + jj * 2, bits);
        }
    }
    __syncthreads();                                       // B5: ef fully consumed
    store_act4(acc, bc1 + r * 128, shT, n16, q, wid, true); // hid -> shT
    __syncthreads();                                       // B6: hid ready

    // ---- phi = hid @ Wc2p[r] / 256 ; wave w covers m-tile w ----
    {
        f32x4 ap = (f32x4)0.f;
        const unsigned short* Bw = Wc2p + (size_t)r * 2048;
#pragma unroll
        for (int c = 0; c < 4; c++) {
            half8 a = *(const half8*)(shT + (wid * 16 + n16) * 136 + c * 32 + ko);
            half8 b = *(const half8*)(Bw + (size_t)(c * 4 + q) * 128 + n16 * 8);
            ap = MFMA16(a, b, ap);
        }
        if (n16 < 4) {
#pragma unroll
            for (int rr = 0; rr < 4; rr++)
                shPhi[(wid * 16 + q * 4 + rr) * 4 + n16] = ap[rr] * (1.0f / 256.0f);
        }
    }
    __syncthreads();                                       // B7: phi ready

    // ---- scatter: sAccum += cd * phi ; cnt (cd from shCd) ----
    {
        const int e = tid >> 2, cc4 = tid & 3;
        const int row = shRow[e];
        const float ph = shPhi[e * 4 + cc4];
#pragma unroll
        for (int d = 0; d < 3; d++) {
            const int idx = cc4 * 3 + d;
            atomicAdd(&sAccum[(size_t)row * 12 + idx], shCd[e * 12 + idx] * ph);
        }
        if (cc4 == 0) atomicAdd(&cnt[row], 1.0f);
    }
}

// ============ node: agg GEMM (seg@Wrel) + node MLP + coord ============
__global__ __launch_bounds__(256, 2) void k_node(
    const float* __restrict__ h, const unsigned short* __restrict__ h_bf,
    const float* __restrict__ coord,
    const unsigned short* __restrict__ seg, const float* __restrict__ sAccum,
    const float* __restrict__ cnt,
    const unsigned short* __restrict__ Wrelp,
    const unsigned short* __restrict__ Wn1p, const float* __restrict__ bn1,
    const unsigned short* __restrict__ Wn2p, const float* __restrict__ bn2,
    float* __restrict__ out, unsigned short* __restrict__ hnew_bf)
{
    __shared__ __align__(16) unsigned short shAgg[64 * 136];
    __shared__ __align__(16) unsigned short shT[64 * 136];
    const int tid = threadIdx.x;
    const int lane = tid & 63, wid = tid >> 6;
    const int n16 = lane & 15, q = lane >> 4;
    const int n0 = blockIdx.x * 64;
    const int ko = q * 8;

    int nodeA[4];
#pragma unroll
    for (int m = 0; m < 4; m++) nodeA[m] = min(n0 + m * 16 + n16, NN - 1);

    f32x4 acc[4][2];
    zero42(acc);
#pragma unroll
    for (int r = 0; r < RR; r++) {
        const unsigned short* segr = seg + (size_t)r * NN * 128;
        const unsigned short* Bp = Wrelp + (size_t)r * 16384;
#pragma unroll
        for (int c = 0; c < 4; c++) {
            half8 a[4];
#pragma unroll
            for (int m = 0; m < 4; m++)
                a[m] = *(const half8*)(segr + (size_t)nodeA[m] * 128 + c * 32 + ko);
            mfma_chunk4(Bp, c, wid, q, n16, a, acc);
        }
    }
#pragma unroll
    for (int i = 0; i < 2; i++) {
        const int n = (2 * wid + i) * 16 + n16;
#pragma unroll
        for (int m = 0; m < 4; m++)
#pragma unroll
            for (int rr = 0; rr < 4; rr++)
                shAgg[(m * 16 + q * 4 + rr) * 136 + n] = f2h(acc[m][i][rr]);
    }
    __syncthreads();

    zero42(acc);
#pragma unroll
    for (int c = 0; c < 4; c++) {
        half8 a[4];
#pragma unroll
        for (int m = 0; m < 4; m++)
            a[m] = *(const half8*)(h_bf + (size_t)nodeA[m] * 128 + c * 32 + ko);
        mfma_chunk4(Wn1p, c, wid, q, n16, a, acc);
    }
#pragma unroll
    for (int c = 4; c < 8; c++) {
        half8 a[4];
#pragma unroll
        for (int m = 0; m < 4; m++)
            a[m] = *(const half8*)(shAgg + (m * 16 + n16) * 136 + (c - 4) * 32 + ko);
        mfma_chunk4(Wn1p, c, wid, q, n16, a, acc);
    }
#pragma unroll
    for (int i = 0; i < 2; i++) {
        const int n = (2 * wid + i) * 16 + n16;
        const float bb = bn1[n];
#pragma unroll
        for (int m = 0; m < 4; m++)
#pragma unroll
            for (int rr = 0; rr < 4; rr++)
                shT[(m * 16 + q * 4 + rr) * 136 + n] = f2h(silu_f(acc[m][i][rr] + bb));
    }
    __syncthreads();

    zero42(acc);
    gemm_lds4<4>(Wn2p, shT, wid, q, n16, acc);
#pragma unroll
    for (int i = 0; i < 2; i++) {
        const int n = (2 * wid + i) * 16 + n16;
        const float bb = bn2[n];
#pragma unroll
        for (int m = 0; m < 4; m++)
#pragma unroll
            for (int rr = 0; rr < 4; rr++) {
                const int node = n0 + m * 16 + q * 4 + rr;
                if (node < NN) {
                    const float v = h[(size_t)node * 128 + n] + acc[m][i][rr] + bb;
                    out[(size_t)node * 128 + n] = v;
                    hnew_bf[(size_t)node * 128 + n] = f2h(v);
                }
            }
    }
    if (tid < 64) {
        const int node = n0 + tid;
        if (node < NN) {
            const float ic = 1.0f / fmaxf(cnt[node], 1.0f);
#pragma unroll
            for (int j2 = 0; j2 < 12; j2++)
                out[OUT_X + (size_t)node * 12 + j2] =
                    coord[(size_t)node * 12 + j2] + sAccum[(size_t)node * 12 + j2] * ic;
        }
    }
}

// ============ edge output m (64 edges/block, R7 verbatim) ============
__global__ __launch_bounds__(256, 2) void k_edge(
    const unsigned short* __restrict__ hnew_bf, const float* __restrict__ eattr,
    const int* __restrict__ edges,
    const unsigned short* __restrict__ We1p, const float* __restrict__ be1,
    const float* __restrict__ We2, const float* __restrict__ be2,
    float* __restrict__ mout)
{
    __shared__ __align__(16) unsigned short shX[64 * 40];
    __shared__ __align__(16) unsigned short shT[64 * 136];
    __shared__ float shW[128];
    __shared__ int shRow[64], shCol[64];
    const int tid = threadIdx.x;
    const int lane = tid & 63, wid = tid >> 6;
    const int n16 = lane & 15, q = lane >> 4;
    const int r = blockIdx.y;
    const int e0 = blockIdx.x * 64;
    const int ko = q * 8;

    if (tid < 64) shRow[tid] = edges[r * 2 * EE + e0 + tid];
    else if (tid < 128) shCol[tid - 64] = edges[r * 2 * EE + EE + e0 + (tid - 64)];
    else shW[tid - 128] = We2[tid - 128];
    __syncthreads();

    if (tid < 64) {
        shX[tid * 40] = f2h(eattr[(size_t)r * EE + e0 + tid]);
#pragma unroll
        for (int k2 = 1; k2 < 32; k2++) shX[tid * 40 + k2] = 0;
    }
    int rowN[4], colN[4];
#pragma unroll
    for (int m = 0; m < 4; m++) {
        rowN[m] = shRow[m * 16 + n16];
        colN[m] = shCol[m * 16 + n16];
    }
    __syncthreads();

    f32x4 acc[4][2];
    zero42(acc);
#pragma unroll
    for (int c = 0; c < 4; c++) {
        half8 a[4];
#pragma unroll
        for (int m = 0; m < 4; m++)
            a[m] = *(const half8*)(hnew_bf + (size_t)rowN[m] * 128 + c * 32 + ko);
        mfma_chunk4(We1p, c, wid, q, n16, a, acc);
    }
#pragma unroll
    for (int c = 0; c < 4; c++) {
        half8 a[4];
#pragma unroll
        for (int m = 0; m < 4; m++)
            a[m] = *(const half8*)(hnew_bf + (size_t)colN[m] * 128 + c * 32 + ko);
        mfma_chunk4(We1p, c + 4, wid, q, n16, a, acc);
    }
    {
        half8 a[4];
#pragma unroll
        for (int m = 0; m < 4; m++)
            a[m] = *(const half8*)(shX + (m * 16 + n16) * 40 + ko);
        mfma_chunk4(We1p, 8, wid, q, n16, a, acc);
    }
    store_act4(acc, be1, shT, n16, q, wid, true);
    __syncthreads();

    const int e = tid >> 2, qq = tid & 3;
    const unsigned short* trow = shT + e * 136 + qq * 32;
    float p = 0.f;
#pragma unroll
    for (int kk4 = 0; kk4 < 8; kk4++) {
        const float4 w4 = *(const float4*)(&shW[qq * 32 + kk4 * 4]);
        p += h2f(trow[kk4*4+0]) * w4.x + h2f(trow[kk4*4+1]) * w4.y
           + h2f(trow[kk4*4+2]) * w4.z + h2f(trow[kk4*4+3]) * w4.w;
    }
    p += __shfl_down(p, 2, 4);
    p += __shfl_down(p, 1, 4);
    if (qq == 0) mout[(size_t)r * EE + e0 + e] = p + be2[0];
}

extern "C" void kernel_launch(void* const* d_in, const int* in_sizes, int n_in,
                              void* d_out, int out_size, void* d_ws, size_t ws_size,
                              hipStream_t stream)
{
    const float* h     = (const float*)d_in[0];
    const float* coord = (const float*)d_in[1];
    const float* eattr = (const float*)d_in[2];
    const int*   edges = (const int*)d_in[3];
    const float* Wm1 = (const float*)d_in[4];
    const float* bm1 = (const float*)d_in[5];
    const float* Wm2 = (const float*)d_in[6];
    const float* bm2 = (const float*)d_in[7];
    const float* We1 = (const float*)d_in[8];
    const float* be1 = (const float*)d_in[9];
    const float* We2 = (const float*)d_in[10];
    const float* be2 = (const float*)d_in[11];
    const float* Wn1 = (const float*)d_in[12];
    const float* bn1 = (const float*)d_in[13];
    const float* Wn2 = (const float*)d_in[14];
    const float* bn2 = (const float*)d_in[15];
    const float* Wrel = (const float*)d_in[16];
    const float* Wc1 = (const float*)d_in[17];
    const float* bc1 = (const float*)d_in[18];
    const float* Wc2 = (const float*)d_in[19];

    float* out = (float*)d_out;
    float* ws  = (float*)d_ws;

    float* nsq      = ws;            // 128 (16/relation used)
    float* inv_norm = ws + 128;      // 128
    float* cnt      = ws + 256;      // 20000
    float* sAccum   = ws + 20256;    // 240000 -> zero region ends at 260256 f32
    unsigned short* U = (unsigned short*)(ws + 260256);
    unsigned short* seg     = U;                   // 20,480,000 (zeroed)
    unsigned short* h_bf    = U + 20480000;
    unsigned short* hnew_bf = U + 23040000;
    unsigned short* Wm1p    = U + 25600000;
    unsigned short* Wm2p    = U + 25636864;
    unsigned short* Wn1p    = U + 25653248;
    unsigned short* Wn2p    = U + 25686016;
    unsigned short* We1p    = U + 25702400;
    unsigned short* Wc1p    = U + 25739264;
    unsigned short* Wrelp   = U + 25870336;
    unsigned short* Wc2p    = U + 26001408;

    hipMemsetAsync(d_ws, 0, (size_t)260256 * 4 + (size_t)20480000 * 2, stream);

    k_cvt_h<<<2500, 256, 0, stream>>>(h, h_bf);
    k_pack_all<<<1632, 256, 0, stream>>>(Wm1, Wm2, Wn1, Wn2, We1, Wc1, Wrel, Wc2,
        Wm1p, Wm2p, Wn1p, Wn2p, We1p, Wc1p, Wrelp, Wc2p);
    k_norm<<<dim3(RR, 32), 256, 0, stream>>>(coord, edges, nsq);
    k_invnorm<<<1, 128, 0, stream>>>(nsq, inv_norm);
    k_msg<<<dim3(EE / 64, RR), 256, 0, stream>>>(h_bf, coord, eattr, edges, inv_norm,
        Wm1p, bm1, Wm2p, bm2, Wc1p, bc1, Wc2p, sAccum, cnt, seg);
    k_node<<<(NN + 63) / 64, 256, 0, stream>>>(h, h_bf, coord, seg, sAccum, cnt,
        Wrelp, Wn1p, bn1, Wn2p, bn2, out, hnew_bf);
    k_edge<<<dim3(EE / 64, RR), 256, 0, stream>>>(hnew_bf, eattr, edges,
        We1p, be1, We2, be2, out + OUT_M);
}